// Round 1
// baseline (465.579 us; speedup 1.0000x reference)
//
#include <hip/hip_runtime.h>

#define N_NODES 20000
#define N_EDGES 640000
#define DIM 128
#define NGRAPH 64

// ---------------------------------------------------------------------------
// K1: v_rel = W3_rel^T @ Wlin, v_root = W3_root^T @ Wlin, cb3 = dot(b3, Wlin)
// ---------------------------------------------------------------------------
__global__ void k_params(const float* __restrict__ W3rel,
                         const float* __restrict__ W3root,
                         const float* __restrict__ b3,
                         const float* __restrict__ Wlin,
                         float* __restrict__ vrel,
                         float* __restrict__ vroot,
                         float* __restrict__ cb3) {
    int k = threadIdx.x;  // 0..127
    float sr = 0.f, so = 0.f;
    for (int h = 0; h < DIM; ++h) {
        float wl = Wlin[h];
        sr = fmaf(wl, W3rel[h * DIM + k], sr);
        so = fmaf(wl, W3root[h * DIM + k], so);
    }
    vrel[k] = sr;
    vroot[k] = so;
    __shared__ float red[DIM];
    red[k] = b3[k] * Wlin[k];
    __syncthreads();
    for (int s = 64; s > 0; s >>= 1) {
        if (k < s) red[k] += red[k + s];
        __syncthreads();
    }
    if (k == 0) cb3[0] = red[0];
}

// ---------------------------------------------------------------------------
// K2: y = x @ W1_rel^T ; r = x @ W1_root^T + b1     (fp32, LDS-tiled 64x64)
// grid = (ceil(N/64), 4), block = 256
// ---------------------------------------------------------------------------
__global__ __launch_bounds__(256, 2) void k_gemm(const float* __restrict__ x,
                                                 const float* __restrict__ Wrel,
                                                 const float* __restrict__ Wroot,
                                                 const float* __restrict__ b1,
                                                 float* __restrict__ y,
                                                 float* __restrict__ r) {
    __shared__ float sA[64][132];  // +4 pad breaks bank aliasing
    __shared__ float sB[64][132];
    const int t = threadIdx.x;
    const int node0 = blockIdx.x * 64;
    const int col0 = blockIdx.y * 64;  // 0..255 combined col space

    // load A tile: 64 node-rows x 128
    for (int ch = 0; ch < 8; ++ch) {
        int idx = ch * 256 + t;  // 0..2047
        int row = idx >> 5;
        int k4 = idx & 31;
        int gn = node0 + row;
        float4 v = make_float4(0.f, 0.f, 0.f, 0.f);
        if (gn < N_NODES) v = ((const float4*)x)[gn * 32 + k4];
        *(float4*)&sA[row][k4 * 4] = v;
    }
    // load B tile: 64 cols x 128 (col c => row c of Wrel or Wroot)
    for (int ch = 0; ch < 8; ++ch) {
        int idx = ch * 256 + t;
        int c = idx >> 5;
        int k4 = idx & 31;
        int gc = col0 + c;
        const float* srcw = (gc < DIM) ? (Wrel + gc * DIM) : (Wroot + (gc - DIM) * DIM);
        float4 v = ((const float4*)srcw)[k4];
        *(float4*)&sB[c][k4 * 4] = v;
    }
    __syncthreads();

    const int tr = (t >> 4) * 4;
    const int tc = (t & 15) * 4;
    float acc[4][4] = {};
    for (int k = 0; k < DIM; k += 4) {
        float4 a[4], b[4];
        for (int i = 0; i < 4; ++i) a[i] = *(const float4*)&sA[tr + i][k];
        for (int j = 0; j < 4; ++j) b[j] = *(const float4*)&sB[tc + j][k];
        for (int i = 0; i < 4; ++i)
            for (int j = 0; j < 4; ++j)
                acc[i][j] = fmaf(a[i].x, b[j].x,
                            fmaf(a[i].y, b[j].y,
                            fmaf(a[i].z, b[j].z,
                            fmaf(a[i].w, b[j].w, acc[i][j]))));
    }

    for (int i = 0; i < 4; ++i) {
        int gn = node0 + tr + i;
        if (gn >= N_NODES) continue;
        int gc = col0 + tc;
        if (gc < DIM) {
            float4 v = make_float4(acc[i][0], acc[i][1], acc[i][2], acc[i][3]);
            *(float4*)&y[gn * DIM + gc] = v;
        } else {
            int c = gc - DIM;
            float4 v = make_float4(acc[i][0] + b1[c], acc[i][1] + b1[c + 1],
                                   acc[i][2] + b1[c + 2], acc[i][3] + b1[c + 3]);
            *(float4*)&r[gn * DIM + c] = v;
        }
    }
}

// ---------------------------------------------------------------------------
// K3: CSR build by dst (count / scan / fill)
// ---------------------------------------------------------------------------
__global__ void k_count(const int* __restrict__ dst, int* __restrict__ cnt) {
    int e = blockIdx.x * 256 + threadIdx.x;
    if (e < N_EDGES) atomicAdd(&cnt[dst[e]], 1);
}

__global__ void k_scan(const int* __restrict__ cnt, int* __restrict__ off,
                       int* __restrict__ cursor) {
    __shared__ int sd[1024];
    __shared__ int carry;
    const int t = threadIdx.x;
    if (t == 0) carry = 0;
    __syncthreads();
    for (int base = 0; base < N_NODES; base += 1024) {
        int i = base + t;
        int v = (i < N_NODES) ? cnt[i] : 0;
        sd[t] = v;
        __syncthreads();
        for (int s = 1; s < 1024; s <<= 1) {
            int add = (t >= s) ? sd[t - s] : 0;
            __syncthreads();
            sd[t] += add;
            __syncthreads();
        }
        int excl = carry + sd[t] - v;
        if (i < N_NODES) { off[i] = excl; cursor[i] = excl; }
        __syncthreads();
        if (t == 0) carry += sd[1023];
        __syncthreads();
    }
    if (t == 0) off[N_NODES] = carry;
}

__global__ void k_fill(const int* __restrict__ dst, int* __restrict__ cursor,
                       int* __restrict__ perm) {
    int e = blockIdx.x * 256 + threadIdx.x;
    if (e < N_EDGES) {
        int p = atomicAdd(&cursor[dst[e]], 1);
        perm[p] = e;
    }
}

// ---------------------------------------------------------------------------
// K4: per-node 128-dim aggregation + fused h1 = relu(.) and scalar dots
//     a[i] = dot(h1_i, vrel), b[i] = dot(h1_i, vroot). 32 lanes per node.
// ---------------------------------------------------------------------------
__global__ __launch_bounds__(256) void k_agg(const float4* __restrict__ y4,
                                             const float4* __restrict__ r4,
                                             const int* __restrict__ off,
                                             const int* __restrict__ perm,
                                             const int* __restrict__ src,
                                             const float* __restrict__ ew,
                                             const float4* __restrict__ vrel4,
                                             const float4* __restrict__ vroot4,
                                             float* __restrict__ aout,
                                             float* __restrict__ bout) {
    const int lane = threadIdx.x & 31;
    const int grp = threadIdx.x >> 5;
    const int node = blockIdx.x * 8 + grp;
    if (node >= N_NODES) return;

    const int e0 = off[node], e1 = off[node + 1];
    float ax = 0.f, ay = 0.f, az = 0.f, aw = 0.f;
    for (int j = e0; j < e1; ++j) {
        int e = perm[j];
        int sn = src[e];
        float w = ew[e];
        float4 v = y4[sn * 32 + lane];
        ax = fmaf(w, v.x, ax);
        ay = fmaf(w, v.y, ay);
        az = fmaf(w, v.z, az);
        aw = fmaf(w, v.w, aw);
    }
    float4 rr = r4[node * 32 + lane];
    float hx = fmaxf(ax + rr.x, 0.f);
    float hy = fmaxf(ay + rr.y, 0.f);
    float hz = fmaxf(az + rr.z, 0.f);
    float hw = fmaxf(aw + rr.w, 0.f);

    float4 vr = vrel4[lane];
    float4 vo = vroot4[lane];
    float pa = hx * vr.x + hy * vr.y + hz * vr.z + hw * vr.w;
    float pb = hx * vo.x + hy * vo.y + hz * vo.z + hw * vo.w;
    for (int m = 16; m > 0; m >>= 1) {
        pa += __shfl_xor(pa, m);
        pb += __shfl_xor(pb, m);
    }
    if (lane == 0) {
        aout[node] = pa;
        bout[node] = pb;
    }
}

// ---------------------------------------------------------------------------
// K5: s_i = sum_{e->i} w_e * a[src_e]; accumulate (s_i + b_i) per graph
// ---------------------------------------------------------------------------
__global__ void k_edge2(const int* __restrict__ off, const int* __restrict__ perm,
                        const int* __restrict__ src, const float* __restrict__ ew,
                        const float* __restrict__ a, const float* __restrict__ b,
                        const int* __restrict__ batch, float* __restrict__ gsum,
                        int* __restrict__ gcnt) {
    int node = blockIdx.x * 256 + threadIdx.x;
    if (node >= N_NODES) return;
    float s = 0.f;
    int e1 = off[node + 1];
    for (int j = off[node]; j < e1; ++j) {
        int e = perm[j];
        s = fmaf(ew[e], a[src[e]], s);
    }
    float val = s + b[node];
    int g = batch[node];
    atomicAdd(&gsum[g], val);
    atomicAdd(&gcnt[g], 1);
}

// ---------------------------------------------------------------------------
// K6: out[g] = relu((gsum + cnt*cb3)/max(cnt,1) + blin)
// ---------------------------------------------------------------------------
__global__ void k_final(const float* __restrict__ gsum, const int* __restrict__ gcnt,
                        const float* __restrict__ cb3, const float* __restrict__ blin,
                        float* __restrict__ out) {
    int g = threadIdx.x;
    if (g >= NGRAPH) return;
    int c = gcnt[g];
    float denom = (c > 0) ? (float)c : 1.f;
    float v = (gsum[g] + (float)c * cb3[0]) / denom + blin[0];
    out[g] = (v > 0.f) ? v : 0.f;
}

// ---------------------------------------------------------------------------
extern "C" void kernel_launch(void* const* d_in, const int* in_sizes, int n_in,
                              void* d_out, int out_size, void* d_ws, size_t ws_size,
                              hipStream_t stream) {
    const float* x = (const float*)d_in[0];
    const int* edge_index = (const int*)d_in[1];
    const int* src = edge_index;             // edge_index[0]
    const int* dst = edge_index + N_EDGES;   // edge_index[1]
    const int* batch = (const int*)d_in[2];
    const float* ew = (const float*)d_in[3];
    const float* W1rel = (const float*)d_in[4];
    const float* b1 = (const float*)d_in[5];
    const float* W1root = (const float*)d_in[6];
    const float* W3rel = (const float*)d_in[7];
    const float* b3 = (const float*)d_in[8];
    const float* W3root = (const float*)d_in[9];
    const float* Wlin = (const float*)d_in[10];
    const float* blin = (const float*)d_in[11];
    float* out = (float*)d_out;

    char* w = (char*)d_ws;
    size_t o = 0;
    auto alloc = [&](size_t bytes) -> void* {
        void* p = w + o;
        o += bytes;
        o = (o + 255) & ~(size_t)255;
        return p;
    };
    float* y = (float*)alloc((size_t)N_NODES * DIM * 4);
    float* r = (float*)alloc((size_t)N_NODES * DIM * 4);
    int* cnt = (int*)alloc((size_t)N_NODES * 4);
    int* off = (int*)alloc((size_t)(N_NODES + 1) * 4);
    int* cursor = (int*)alloc((size_t)N_NODES * 4);
    int* perm = (int*)alloc((size_t)N_EDGES * 4);
    float* a = (float*)alloc((size_t)N_NODES * 4);
    float* b = (float*)alloc((size_t)N_NODES * 4);
    float* vrel = (float*)alloc(DIM * 4);
    float* vroot = (float*)alloc(DIM * 4);
    float* cb3 = (float*)alloc(4);
    float* gsum = (float*)alloc(NGRAPH * 4);
    int* gcnt = (int*)alloc(NGRAPH * 4);

    hipMemsetAsync(cnt, 0, (size_t)N_NODES * 4, stream);
    hipMemsetAsync(gsum, 0, NGRAPH * 4, stream);
    hipMemsetAsync(gcnt, 0, NGRAPH * 4, stream);

    k_params<<<1, 128, 0, stream>>>(W3rel, W3root, b3, Wlin, vrel, vroot, cb3);

    dim3 gemm_grid((N_NODES + 63) / 64, 4);
    k_gemm<<<gemm_grid, 256, 0, stream>>>(x, W1rel, W1root, b1, y, r);

    int eb = (N_EDGES + 255) / 256;
    k_count<<<eb, 256, 0, stream>>>(dst, cnt);
    k_scan<<<1, 1024, 0, stream>>>(cnt, off, cursor);
    k_fill<<<eb, 256, 0, stream>>>(dst, cursor, perm);

    k_agg<<<(N_NODES + 7) / 8, 256, 0, stream>>>((const float4*)y, (const float4*)r,
                                                 off, perm, src, ew,
                                                 (const float4*)vrel, (const float4*)vroot,
                                                 a, b);

    k_edge2<<<(N_NODES + 255) / 256, 256, 0, stream>>>(off, perm, src, ew, a, b,
                                                       batch, gsum, gcnt);

    k_final<<<1, 64, 0, stream>>>(gsum, gcnt, cb3, blin, out);
}

// Round 2
// 286.307 us; speedup vs baseline: 1.6262x; 1.6262x over previous
//
#include <hip/hip_runtime.h>

#define N_NODES 20000
#define N_EDGES 640000
#define DIM 128
#define NGRAPH 64

// ---------------------------------------------------------------------------
// K1: v_rel = W3_rel^T @ Wlin, v_root = W3_root^T @ Wlin, cb3 = dot(b3, Wlin)
// ---------------------------------------------------------------------------
__global__ void k_params(const float* __restrict__ W3rel,
                         const float* __restrict__ W3root,
                         const float* __restrict__ b3,
                         const float* __restrict__ Wlin,
                         float* __restrict__ vrel,
                         float* __restrict__ vroot,
                         float* __restrict__ cb3) {
    int k = threadIdx.x;  // 0..127
    float sr = 0.f, so = 0.f;
    for (int h = 0; h < DIM; ++h) {
        float wl = Wlin[h];
        sr = fmaf(wl, W3rel[h * DIM + k], sr);
        so = fmaf(wl, W3root[h * DIM + k], so);
    }
    vrel[k] = sr;
    vroot[k] = so;
    __shared__ float red[DIM];
    red[k] = b3[k] * Wlin[k];
    __syncthreads();
    for (int s = 64; s > 0; s >>= 1) {
        if (k < s) red[k] += red[k + s];
        __syncthreads();
    }
    if (k == 0) cb3[0] = red[0];
}

// ---------------------------------------------------------------------------
// K2: y = x @ W1_rel^T ; r = x @ W1_root^T + b1     (fp32, LDS-tiled 64x64)
// ---------------------------------------------------------------------------
__global__ __launch_bounds__(256, 2) void k_gemm(const float* __restrict__ x,
                                                 const float* __restrict__ Wrel,
                                                 const float* __restrict__ Wroot,
                                                 const float* __restrict__ b1,
                                                 float* __restrict__ y,
                                                 float* __restrict__ r) {
    __shared__ float sA[64][132];
    __shared__ float sB[64][132];
    const int t = threadIdx.x;
    const int node0 = blockIdx.x * 64;
    const int col0 = blockIdx.y * 64;

    for (int ch = 0; ch < 8; ++ch) {
        int idx = ch * 256 + t;
        int row = idx >> 5;
        int k4 = idx & 31;
        int gn = node0 + row;
        float4 v = make_float4(0.f, 0.f, 0.f, 0.f);
        if (gn < N_NODES) v = ((const float4*)x)[gn * 32 + k4];
        *(float4*)&sA[row][k4 * 4] = v;
    }
    for (int ch = 0; ch < 8; ++ch) {
        int idx = ch * 256 + t;
        int c = idx >> 5;
        int k4 = idx & 31;
        int gc = col0 + c;
        const float* srcw = (gc < DIM) ? (Wrel + gc * DIM) : (Wroot + (gc - DIM) * DIM);
        float4 v = ((const float4*)srcw)[k4];
        *(float4*)&sB[c][k4 * 4] = v;
    }
    __syncthreads();

    const int tr = (t >> 4) * 4;
    const int tc = (t & 15) * 4;
    float acc[4][4] = {};
    for (int k = 0; k < DIM; k += 4) {
        float4 a[4], b[4];
        for (int i = 0; i < 4; ++i) a[i] = *(const float4*)&sA[tr + i][k];
        for (int j = 0; j < 4; ++j) b[j] = *(const float4*)&sB[tc + j][k];
        for (int i = 0; i < 4; ++i)
            for (int j = 0; j < 4; ++j)
                acc[i][j] = fmaf(a[i].x, b[j].x,
                            fmaf(a[i].y, b[j].y,
                            fmaf(a[i].z, b[j].z,
                            fmaf(a[i].w, b[j].w, acc[i][j]))));
    }

    for (int i = 0; i < 4; ++i) {
        int gn = node0 + tr + i;
        if (gn >= N_NODES) continue;
        int gc = col0 + tc;
        if (gc < DIM) {
            float4 v = make_float4(acc[i][0], acc[i][1], acc[i][2], acc[i][3]);
            *(float4*)&y[gn * DIM + gc] = v;
        } else {
            int c = gc - DIM;
            float4 v = make_float4(acc[i][0] + b1[c], acc[i][1] + b1[c + 1],
                                   acc[i][2] + b1[c + 2], acc[i][3] + b1[c + 3]);
            *(float4*)&r[gn * DIM + c] = v;
        }
    }
}

// ---------------------------------------------------------------------------
// K3: CSR build by dst (count / scan / fill-with-gather)
// ---------------------------------------------------------------------------
__global__ void k_count(const int* __restrict__ dst, int* __restrict__ cnt) {
    int e = blockIdx.x * 256 + threadIdx.x;
    if (e < N_EDGES) atomicAdd(&cnt[dst[e]], 1);
}

#define SCAN_T 1024
#define PER_T 20  // 1024*20 = 20480 >= 20000
__global__ __launch_bounds__(SCAN_T) void k_scan(const int* __restrict__ cnt,
                                                 int* __restrict__ off,
                                                 int* __restrict__ cursor) {
    const int t = threadIdx.x;
    const int base = t * PER_T;
    int vals[PER_T];
    int tot = 0;
    for (int i = 0; i < PER_T; ++i) {
        int idx = base + i;
        int v = (idx < N_NODES) ? cnt[idx] : 0;
        vals[i] = v;
        tot += v;
    }
    // inclusive wave scan (64 lanes)
    const int lane = t & 63;
    const int wid = t >> 6;  // 0..15
    int xs = tot;
    for (int s = 1; s < 64; s <<= 1) {
        int u = __shfl_up(xs, s);
        if (lane >= s) xs += u;
    }
    __shared__ int wsum[16];
    if (lane == 63) wsum[wid] = xs;
    __syncthreads();
    if (t < 16) {
        int wv = wsum[t];
        for (int s = 1; s < 16; s <<= 1) {
            int u = __shfl_up(wv, s);
            if (t >= s) wv += u;
        }
        wsum[t] = wv;  // inclusive over wave totals
    }
    __syncthreads();
    int wbase = (wid > 0) ? wsum[wid - 1] : 0;
    int run = wbase + xs - tot;  // exclusive prefix for this thread
    for (int i = 0; i < PER_T; ++i) {
        int idx = base + i;
        if (idx < N_NODES) {
            off[idx] = run;
            cursor[idx] = run;
        }
        run += vals[i];
    }
    if (t == SCAN_T - 1) off[N_NODES] = run;
}

__global__ void k_fill(const int* __restrict__ src, const int* __restrict__ dst,
                       const float* __restrict__ ew, int* __restrict__ cursor,
                       int* __restrict__ gsrc, float* __restrict__ gw) {
    int e = blockIdx.x * 256 + threadIdx.x;
    if (e < N_EDGES) {
        int p = atomicAdd(&cursor[dst[e]], 1);
        gsrc[p] = src[e];
        gw[p] = ew[e];
    }
}

// ---------------------------------------------------------------------------
// K4: per-node aggregation, one 64-lane wave per node, float2 per lane.
//     h1 = relu(agg + r); a[i] = h1.vrel; b[i] = h1.vroot
// ---------------------------------------------------------------------------
__global__ __launch_bounds__(256) void k_agg(const float2* __restrict__ y2,
                                             const float2* __restrict__ r2,
                                             const int* __restrict__ off,
                                             const int* __restrict__ gsrc,
                                             const float* __restrict__ gw,
                                             const float2* __restrict__ vrel2,
                                             const float2* __restrict__ vroot2,
                                             float* __restrict__ aout,
                                             float* __restrict__ bout) {
    const int lane = threadIdx.x & 63;
    const int node = blockIdx.x * 4 + (threadIdx.x >> 6);
    if (node >= N_NODES) return;

    int j = off[node];
    const int e1 = off[node + 1];
    float sx = 0.f, sy = 0.f;
    // 4x unrolled: 4 independent y-row loads in flight
    for (; j + 4 <= e1; j += 4) {
        int s0 = gsrc[j], s1 = gsrc[j + 1], s2 = gsrc[j + 2], s3 = gsrc[j + 3];
        float w0 = gw[j], w1 = gw[j + 1], w2 = gw[j + 2], w3 = gw[j + 3];
        float2 v0 = y2[(size_t)s0 * 64 + lane];
        float2 v1 = y2[(size_t)s1 * 64 + lane];
        float2 v2 = y2[(size_t)s2 * 64 + lane];
        float2 v3 = y2[(size_t)s3 * 64 + lane];
        sx = fmaf(w0, v0.x, fmaf(w1, v1.x, fmaf(w2, v2.x, fmaf(w3, v3.x, sx))));
        sy = fmaf(w0, v0.y, fmaf(w1, v1.y, fmaf(w2, v2.y, fmaf(w3, v3.y, sy))));
    }
    for (; j < e1; ++j) {
        int s = gsrc[j];
        float w = gw[j];
        float2 v = y2[(size_t)s * 64 + lane];
        sx = fmaf(w, v.x, sx);
        sy = fmaf(w, v.y, sy);
    }
    float2 rr = r2[(size_t)node * 64 + lane];
    float hx = fmaxf(sx + rr.x, 0.f);
    float hy = fmaxf(sy + rr.y, 0.f);
    float2 vr = vrel2[lane];
    float2 vo = vroot2[lane];
    float pa = hx * vr.x + hy * vr.y;
    float pb = hx * vo.x + hy * vo.y;
    for (int m = 32; m > 0; m >>= 1) {
        pa += __shfl_xor(pa, m);
        pb += __shfl_xor(pb, m);
    }
    if (lane == 0) {
        aout[node] = pa;
        bout[node] = pb;
    }
}

// ---------------------------------------------------------------------------
// K5a: edge-parallel: gsum[batch[dst_e]] += w_e * a[src_e]  (LDS-binned)
// ---------------------------------------------------------------------------
__global__ __launch_bounds__(256) void k_edge_reduce(const int* __restrict__ src,
                                                     const int* __restrict__ dst,
                                                     const float* __restrict__ ew,
                                                     const float* __restrict__ a,
                                                     const int* __restrict__ batch,
                                                     float* __restrict__ gsum) {
    __shared__ float bins[NGRAPH];
    for (int i = threadIdx.x; i < NGRAPH; i += 256) bins[i] = 0.f;
    __syncthreads();
    for (int e = blockIdx.x * 256 + threadIdx.x; e < N_EDGES; e += gridDim.x * 256) {
        float v = ew[e] * a[src[e]];
        int g = batch[dst[e]];
        atomicAdd(&bins[g], v);
    }
    __syncthreads();
    for (int i = threadIdx.x; i < NGRAPH; i += 256) atomicAdd(&gsum[i], bins[i]);
}

// ---------------------------------------------------------------------------
// K5b: node-parallel: gsum[batch[i]] += b[i]; gcnt[batch[i]] += 1
// ---------------------------------------------------------------------------
__global__ __launch_bounds__(256) void k_node_reduce(const float* __restrict__ b,
                                                     const int* __restrict__ batch,
                                                     float* __restrict__ gsum,
                                                     int* __restrict__ gcnt) {
    __shared__ float sbin[NGRAPH];
    __shared__ int cbin[NGRAPH];
    for (int i = threadIdx.x; i < NGRAPH; i += 256) { sbin[i] = 0.f; cbin[i] = 0; }
    __syncthreads();
    for (int n = blockIdx.x * 256 + threadIdx.x; n < N_NODES; n += gridDim.x * 256) {
        int g = batch[n];
        atomicAdd(&sbin[g], b[n]);
        atomicAdd(&cbin[g], 1);
    }
    __syncthreads();
    for (int i = threadIdx.x; i < NGRAPH; i += 256) {
        atomicAdd(&gsum[i], sbin[i]);
        atomicAdd(&gcnt[i], cbin[i]);
    }
}

// ---------------------------------------------------------------------------
// K6: out[g] = relu((gsum + cnt*cb3)/max(cnt,1) + blin)
// ---------------------------------------------------------------------------
__global__ void k_final(const float* __restrict__ gsum, const int* __restrict__ gcnt,
                        const float* __restrict__ cb3, const float* __restrict__ blin,
                        float* __restrict__ out) {
    int g = threadIdx.x;
    if (g >= NGRAPH) return;
    int c = gcnt[g];
    float denom = (c > 0) ? (float)c : 1.f;
    float v = (gsum[g] + (float)c * cb3[0]) / denom + blin[0];
    out[g] = (v > 0.f) ? v : 0.f;
}

// ---------------------------------------------------------------------------
extern "C" void kernel_launch(void* const* d_in, const int* in_sizes, int n_in,
                              void* d_out, int out_size, void* d_ws, size_t ws_size,
                              hipStream_t stream) {
    const float* x = (const float*)d_in[0];
    const int* edge_index = (const int*)d_in[1];
    const int* src = edge_index;
    const int* dst = edge_index + N_EDGES;
    const int* batch = (const int*)d_in[2];
    const float* ew = (const float*)d_in[3];
    const float* W1rel = (const float*)d_in[4];
    const float* b1 = (const float*)d_in[5];
    const float* W1root = (const float*)d_in[6];
    const float* W3rel = (const float*)d_in[7];
    const float* b3 = (const float*)d_in[8];
    const float* W3root = (const float*)d_in[9];
    const float* Wlin = (const float*)d_in[10];
    const float* blin = (const float*)d_in[11];
    float* out = (float*)d_out;

    char* w = (char*)d_ws;
    size_t o = 0;
    auto alloc = [&](size_t bytes) -> void* {
        void* p = w + o;
        o += bytes;
        o = (o + 255) & ~(size_t)255;
        return p;
    };
    float* y = (float*)alloc((size_t)N_NODES * DIM * 4);
    float* r = (float*)alloc((size_t)N_NODES * DIM * 4);
    int* cnt = (int*)alloc((size_t)N_NODES * 4);
    int* off = (int*)alloc((size_t)(N_NODES + 1) * 4);
    int* cursor = (int*)alloc((size_t)N_NODES * 4);
    int* gsrc = (int*)alloc((size_t)N_EDGES * 4);
    float* gw = (float*)alloc((size_t)N_EDGES * 4);
    float* a = (float*)alloc((size_t)N_NODES * 4);
    float* b = (float*)alloc((size_t)N_NODES * 4);
    float* vrel = (float*)alloc(DIM * 4);
    float* vroot = (float*)alloc(DIM * 4);
    float* cb3 = (float*)alloc(4);
    float* gsum = (float*)alloc(NGRAPH * 4);
    int* gcnt = (int*)alloc(NGRAPH * 4);

    hipMemsetAsync(cnt, 0, (size_t)N_NODES * 4, stream);
    hipMemsetAsync(gsum, 0, NGRAPH * 4, stream);
    hipMemsetAsync(gcnt, 0, NGRAPH * 4, stream);

    k_params<<<1, 128, 0, stream>>>(W3rel, W3root, b3, Wlin, vrel, vroot, cb3);

    dim3 gemm_grid((N_NODES + 63) / 64, 4);
    k_gemm<<<gemm_grid, 256, 0, stream>>>(x, W1rel, W1root, b1, y, r);

    int eb = (N_EDGES + 255) / 256;
    k_count<<<eb, 256, 0, stream>>>(dst, cnt);
    k_scan<<<1, SCAN_T, 0, stream>>>(cnt, off, cursor);
    k_fill<<<eb, 256, 0, stream>>>(src, dst, ew, cursor, gsrc, gw);

    k_agg<<<(N_NODES + 3) / 4, 256, 0, stream>>>((const float2*)y, (const float2*)r,
                                                 off, gsrc, gw,
                                                 (const float2*)vrel, (const float2*)vroot,
                                                 a, b);

    k_edge_reduce<<<512, 256, 0, stream>>>(src, dst, ew, a, batch, gsum);
    k_node_reduce<<<64, 256, 0, stream>>>(b, batch, gsum, gcnt);

    k_final<<<1, 64, 0, stream>>>(gsum, gcnt, cb3, blin, out);
}

// Round 3
// 275.176 us; speedup vs baseline: 1.6919x; 1.0405x over previous
//
#include <hip/hip_runtime.h>

#define N_NODES 20000
#define N_EDGES 640000
#define DIM 128
#define NGRAPH 64

// ---------------------------------------------------------------------------
// K1: v_rel = W3_rel^T @ Wlin, v_root = W3_root^T @ Wlin, cb3 = dot(b3, Wlin)
// ---------------------------------------------------------------------------
__global__ void k_params(const float* __restrict__ W3rel,
                         const float* __restrict__ W3root,
                         const float* __restrict__ b3,
                         const float* __restrict__ Wlin,
                         float* __restrict__ vrel,
                         float* __restrict__ vroot,
                         float* __restrict__ cb3) {
    int k = threadIdx.x;  // 0..127
    float sr = 0.f, so = 0.f;
    for (int h = 0; h < DIM; ++h) {
        float wl = Wlin[h];
        sr = fmaf(wl, W3rel[h * DIM + k], sr);
        so = fmaf(wl, W3root[h * DIM + k], so);
    }
    vrel[k] = sr;
    vroot[k] = so;
    __shared__ float red[DIM];
    red[k] = b3[k] * Wlin[k];
    __syncthreads();
    for (int s = 64; s > 0; s >>= 1) {
        if (k < s) red[k] += red[k + s];
        __syncthreads();
    }
    if (k == 0) cb3[0] = red[0];
}

// ---------------------------------------------------------------------------
// K2: y = x @ W1_rel^T ; r = x @ W1_root^T + b1     (fp32, LDS-tiled 64x64)
// ---------------------------------------------------------------------------
__global__ __launch_bounds__(256, 2) void k_gemm(const float* __restrict__ x,
                                                 const float* __restrict__ Wrel,
                                                 const float* __restrict__ Wroot,
                                                 const float* __restrict__ b1,
                                                 float* __restrict__ y,
                                                 float* __restrict__ r) {
    __shared__ float sA[64][132];
    __shared__ float sB[64][132];
    const int t = threadIdx.x;
    const int node0 = blockIdx.x * 64;
    const int col0 = blockIdx.y * 64;

    for (int ch = 0; ch < 8; ++ch) {
        int idx = ch * 256 + t;
        int row = idx >> 5;
        int k4 = idx & 31;
        int gn = node0 + row;
        float4 v = make_float4(0.f, 0.f, 0.f, 0.f);
        if (gn < N_NODES) v = ((const float4*)x)[gn * 32 + k4];
        *(float4*)&sA[row][k4 * 4] = v;
    }
    for (int ch = 0; ch < 8; ++ch) {
        int idx = ch * 256 + t;
        int c = idx >> 5;
        int k4 = idx & 31;
        int gc = col0 + c;
        const float* srcw = (gc < DIM) ? (Wrel + gc * DIM) : (Wroot + (gc - DIM) * DIM);
        float4 v = ((const float4*)srcw)[k4];
        *(float4*)&sB[c][k4 * 4] = v;
    }
    __syncthreads();

    const int tr = (t >> 4) * 4;
    const int tc = (t & 15) * 4;
    float acc[4][4] = {};
    for (int k = 0; k < DIM; k += 4) {
        float4 a[4], b[4];
        for (int i = 0; i < 4; ++i) a[i] = *(const float4*)&sA[tr + i][k];
        for (int j = 0; j < 4; ++j) b[j] = *(const float4*)&sB[tc + j][k];
        for (int i = 0; i < 4; ++i)
            for (int j = 0; j < 4; ++j)
                acc[i][j] = fmaf(a[i].x, b[j].x,
                            fmaf(a[i].y, b[j].y,
                            fmaf(a[i].z, b[j].z,
                            fmaf(a[i].w, b[j].w, acc[i][j]))));
    }

    for (int i = 0; i < 4; ++i) {
        int gn = node0 + tr + i;
        if (gn >= N_NODES) continue;
        int gc = col0 + tc;
        if (gc < DIM) {
            float4 v = make_float4(acc[i][0], acc[i][1], acc[i][2], acc[i][3]);
            *(float4*)&y[gn * DIM + gc] = v;
        } else {
            int c = gc - DIM;
            float4 v = make_float4(acc[i][0] + b1[c], acc[i][1] + b1[c + 1],
                                   acc[i][2] + b1[c + 2], acc[i][3] + b1[c + 3]);
            *(float4*)&r[gn * DIM + c] = v;
        }
    }
}

// ---------------------------------------------------------------------------
// K3: CSR build by dst (count / scan / fill packed (src,w) records)
// ---------------------------------------------------------------------------
__global__ void k_count(const int* __restrict__ dst, int* __restrict__ cnt) {
    int e = blockIdx.x * 256 + threadIdx.x;
    if (e < N_EDGES) atomicAdd(&cnt[dst[e]], 1);
}

#define SCAN_T 1024
#define PER_T 20  // 1024*20 = 20480 >= 20000
__global__ __launch_bounds__(SCAN_T) void k_scan(const int* __restrict__ cnt,
                                                 int* __restrict__ off,
                                                 int* __restrict__ cursor) {
    const int t = threadIdx.x;
    const int base = t * PER_T;
    int vals[PER_T];
    int tot = 0;
    for (int i = 0; i < PER_T; ++i) {
        int idx = base + i;
        int v = (idx < N_NODES) ? cnt[idx] : 0;
        vals[i] = v;
        tot += v;
    }
    const int lane = t & 63;
    const int wid = t >> 6;  // 0..15
    int xs = tot;
    for (int s = 1; s < 64; s <<= 1) {
        int u = __shfl_up(xs, s);
        if (lane >= s) xs += u;
    }
    __shared__ int wsum[16];
    if (lane == 63) wsum[wid] = xs;
    __syncthreads();
    if (t < 16) {
        int wv = wsum[t];
        for (int s = 1; s < 16; s <<= 1) {
            int u = __shfl_up(wv, s);
            if (t >= s) wv += u;
        }
        wsum[t] = wv;
    }
    __syncthreads();
    int wbase = (wid > 0) ? wsum[wid - 1] : 0;
    int run = wbase + xs - tot;
    for (int i = 0; i < PER_T; ++i) {
        int idx = base + i;
        if (idx < N_NODES) {
            off[idx] = run;
            cursor[idx] = run;
        }
        run += vals[i];
    }
    if (t == SCAN_T - 1) off[N_NODES] = run;
}

__global__ void k_fill(const int* __restrict__ src, const int* __restrict__ dst,
                       const float* __restrict__ ew, int* __restrict__ cursor,
                       int2* __restrict__ grec) {
    int e = blockIdx.x * 256 + threadIdx.x;
    if (e < N_EDGES) {
        int p = atomicAdd(&cursor[dst[e]], 1);
        grec[p] = make_int2(src[e], __float_as_int(ew[e]));  // one 8B store
    }
}

// ---------------------------------------------------------------------------
// K4: per-node aggregation, one 64-lane wave per node, float2 per lane.
//     h1 = relu(agg + r); a[i] = h1.vrel; b[i] = h1.vroot
// ---------------------------------------------------------------------------
__global__ __launch_bounds__(256) void k_agg(const float2* __restrict__ y2,
                                             const float2* __restrict__ r2,
                                             const int* __restrict__ off,
                                             const int2* __restrict__ grec,
                                             const float2* __restrict__ vrel2,
                                             const float2* __restrict__ vroot2,
                                             float* __restrict__ aout,
                                             float* __restrict__ bout) {
    const int lane = threadIdx.x & 63;
    const int node = blockIdx.x * 4 + (threadIdx.x >> 6);
    if (node >= N_NODES) return;

    int j = off[node];
    const int e1 = off[node + 1];
    float sx = 0.f, sy = 0.f;
    for (; j + 4 <= e1; j += 4) {
        int2 r0 = grec[j], r1 = grec[j + 1], r2_ = grec[j + 2], r3 = grec[j + 3];
        float w0 = __int_as_float(r0.y), w1 = __int_as_float(r1.y);
        float w2 = __int_as_float(r2_.y), w3 = __int_as_float(r3.y);
        float2 v0 = y2[(size_t)r0.x * 64 + lane];
        float2 v1 = y2[(size_t)r1.x * 64 + lane];
        float2 v2 = y2[(size_t)r2_.x * 64 + lane];
        float2 v3 = y2[(size_t)r3.x * 64 + lane];
        sx = fmaf(w0, v0.x, fmaf(w1, v1.x, fmaf(w2, v2.x, fmaf(w3, v3.x, sx))));
        sy = fmaf(w0, v0.y, fmaf(w1, v1.y, fmaf(w2, v2.y, fmaf(w3, v3.y, sy))));
    }
    for (; j < e1; ++j) {
        int2 rc = grec[j];
        float w = __int_as_float(rc.y);
        float2 v = y2[(size_t)rc.x * 64 + lane];
        sx = fmaf(w, v.x, sx);
        sy = fmaf(w, v.y, sy);
    }
    float2 rr = r2[(size_t)node * 64 + lane];
    float hx = fmaxf(sx + rr.x, 0.f);
    float hy = fmaxf(sy + rr.y, 0.f);
    float2 vr = vrel2[lane];
    float2 vo = vroot2[lane];
    float pa = hx * vr.x + hy * vr.y;
    float pb = hx * vo.x + hy * vo.y;
    for (int m = 32; m > 0; m >>= 1) {
        pa += __shfl_xor(pa, m);
        pb += __shfl_xor(pb, m);
    }
    if (lane == 0) {
        aout[node] = pa;
        bout[node] = pb;
    }
}

// ---------------------------------------------------------------------------
// K5: fused reduce: gsum[batch[dst_e]] += w_e*a[src_e];
//                   gsum[batch[i]] += b[i]; gcnt[batch[i]] += 1
// ---------------------------------------------------------------------------
__global__ __launch_bounds__(256) void k_reduce(const int* __restrict__ src,
                                                const int* __restrict__ dst,
                                                const float* __restrict__ ew,
                                                const float* __restrict__ a,
                                                const float* __restrict__ b,
                                                const int* __restrict__ batch,
                                                float* __restrict__ gsum,
                                                int* __restrict__ gcnt) {
    __shared__ float sbin[NGRAPH];
    __shared__ int cbin[NGRAPH];
    for (int i = threadIdx.x; i < NGRAPH; i += 256) { sbin[i] = 0.f; cbin[i] = 0; }
    __syncthreads();
    for (int e = blockIdx.x * 256 + threadIdx.x; e < N_EDGES; e += gridDim.x * 256) {
        float v = ew[e] * a[src[e]];
        atomicAdd(&sbin[batch[dst[e]]], v);
    }
    for (int n = blockIdx.x * 256 + threadIdx.x; n < N_NODES; n += gridDim.x * 256) {
        int g = batch[n];
        atomicAdd(&sbin[g], b[n]);
        atomicAdd(&cbin[g], 1);
    }
    __syncthreads();
    for (int i = threadIdx.x; i < NGRAPH; i += 256) {
        atomicAdd(&gsum[i], sbin[i]);
        if (cbin[i]) atomicAdd(&gcnt[i], cbin[i]);
    }
}

// ---------------------------------------------------------------------------
// K6: out[g] = relu((gsum + cnt*cb3)/max(cnt,1) + blin)
// ---------------------------------------------------------------------------
__global__ void k_final(const float* __restrict__ gsum, const int* __restrict__ gcnt,
                        const float* __restrict__ cb3, const float* __restrict__ blin,
                        float* __restrict__ out) {
    int g = threadIdx.x;
    if (g >= NGRAPH) return;
    int c = gcnt[g];
    float denom = (c > 0) ? (float)c : 1.f;
    float v = (gsum[g] + (float)c * cb3[0]) / denom + blin[0];
    out[g] = (v > 0.f) ? v : 0.f;
}

// ---------------------------------------------------------------------------
extern "C" void kernel_launch(void* const* d_in, const int* in_sizes, int n_in,
                              void* d_out, int out_size, void* d_ws, size_t ws_size,
                              hipStream_t stream) {
    const float* x = (const float*)d_in[0];
    const int* edge_index = (const int*)d_in[1];
    const int* src = edge_index;
    const int* dst = edge_index + N_EDGES;
    const int* batch = (const int*)d_in[2];
    const float* ew = (const float*)d_in[3];
    const float* W1rel = (const float*)d_in[4];
    const float* b1 = (const float*)d_in[5];
    const float* W1root = (const float*)d_in[6];
    const float* W3rel = (const float*)d_in[7];
    const float* b3 = (const float*)d_in[8];
    const float* W3root = (const float*)d_in[9];
    const float* Wlin = (const float*)d_in[10];
    const float* blin = (const float*)d_in[11];
    float* out = (float*)d_out;

    char* w = (char*)d_ws;
    size_t o = 0;
    auto alloc = [&](size_t bytes) -> void* {
        void* p = w + o;
        o += bytes;
        o = (o + 255) & ~(size_t)255;
        return p;
    };
    float* y = (float*)alloc((size_t)N_NODES * DIM * 4);
    float* r = (float*)alloc((size_t)N_NODES * DIM * 4);
    int* cnt = (int*)alloc((size_t)N_NODES * 4);
    int* off = (int*)alloc((size_t)(N_NODES + 1) * 4);
    int* cursor = (int*)alloc((size_t)N_NODES * 4);
    int2* grec = (int2*)alloc((size_t)N_EDGES * 8);
    float* a = (float*)alloc((size_t)N_NODES * 4);
    float* b = (float*)alloc((size_t)N_NODES * 4);
    float* vrel = (float*)alloc(DIM * 4);
    float* vroot = (float*)alloc(DIM * 4);
    float* cb3 = (float*)alloc(4);
    float* gsum = (float*)alloc(NGRAPH * 4);
    int* gcnt = (int*)alloc(NGRAPH * 4);

    hipMemsetAsync(cnt, 0, (size_t)N_NODES * 4, stream);
    hipMemsetAsync(gsum, 0, NGRAPH * 4, stream);
    hipMemsetAsync(gcnt, 0, NGRAPH * 4, stream);

    k_params<<<1, 128, 0, stream>>>(W3rel, W3root, b3, Wlin, vrel, vroot, cb3);

    dim3 gemm_grid((N_NODES + 63) / 64, 4);
    k_gemm<<<gemm_grid, 256, 0, stream>>>(x, W1rel, W1root, b1, y, r);

    int eb = (N_EDGES + 255) / 256;
    k_count<<<eb, 256, 0, stream>>>(dst, cnt);
    k_scan<<<1, SCAN_T, 0, stream>>>(cnt, off, cursor);
    k_fill<<<eb, 256, 0, stream>>>(src, dst, ew, cursor, grec);

    k_agg<<<(N_NODES + 3) / 4, 256, 0, stream>>>((const float2*)y, (const float2*)r,
                                                 off, grec,
                                                 (const float2*)vrel, (const float2*)vroot,
                                                 a, b);

    k_reduce<<<512, 256, 0, stream>>>(src, dst, ew, a, b, batch, gsum, gcnt);

    k_final<<<1, 64, 0, stream>>>(gsum, gcnt, cb3, blin, out);
}

// Round 4
// 214.706 us; speedup vs baseline: 2.1684x; 1.2816x over previous
//
#include <hip/hip_runtime.h>

#define N_NODES 20000
#define N_EDGES 640000
#define DIM 128
#define NGRAPH 64
#define NBUCK 313          // ceil(20000/64) dst buckets of 64 nodes
#define EPB 2048           // edges per histogram/partition block
#define NB_GEMM 1252       // 313 node-tiles x 4 col-tiles
#define NB_HIST 313        // ceil(640000/2048)
#define RED_BLOCKS 512

// ---------------------------------------------------------------------------
// K_front: fused [GEMM | dst-bucket histogram (+scan via last-block ticket) | params]
// ---------------------------------------------------------------------------
__global__ __launch_bounds__(256, 2) void k_front(
    const float* __restrict__ x, const float* __restrict__ Wrel,
    const float* __restrict__ Wroot, const float* __restrict__ b1,
    float* __restrict__ y, float* __restrict__ r,
    const int* __restrict__ dst,
    int* __restrict__ ghist, int* __restrict__ ticket_hist,
    int* __restrict__ boff, int* __restrict__ gcursor,
    const float* __restrict__ W3rel, const float* __restrict__ W3root,
    const float* __restrict__ b3, const float* __restrict__ Wlin,
    float* __restrict__ vrel, float* __restrict__ vroot, float* __restrict__ cb3) {

    __shared__ float sA[64][132];
    __shared__ float sB[64][132];
    __shared__ int lhist[NBUCK];
    __shared__ int islast;

    const int t = threadIdx.x;
    const int blk = blockIdx.x;

    if (blk < NB_GEMM) {
        // ------------------- GEMM: y = x W1rel^T, r = x W1root^T + b1 -------
        const int node0 = (blk % 313) * 64;
        const int col0 = (blk / 313) * 64;

        for (int ch = 0; ch < 8; ++ch) {
            int idx = ch * 256 + t;
            int row = idx >> 5;
            int k4 = idx & 31;
            int gn = node0 + row;
            float4 v = make_float4(0.f, 0.f, 0.f, 0.f);
            if (gn < N_NODES) v = ((const float4*)x)[gn * 32 + k4];
            *(float4*)&sA[row][k4 * 4] = v;
        }
        for (int ch = 0; ch < 8; ++ch) {
            int idx = ch * 256 + t;
            int c = idx >> 5;
            int k4 = idx & 31;
            int gc = col0 + c;
            const float* srcw = (gc < DIM) ? (Wrel + gc * DIM) : (Wroot + (gc - DIM) * DIM);
            float4 v = ((const float4*)srcw)[k4];
            *(float4*)&sB[c][k4 * 4] = v;
        }
        __syncthreads();

        const int tr = (t >> 4) * 4;
        const int tc = (t & 15) * 4;
        float acc[4][4] = {};
        for (int k = 0; k < DIM; k += 4) {
            float4 a[4], b[4];
            for (int i = 0; i < 4; ++i) a[i] = *(const float4*)&sA[tr + i][k];
            for (int j = 0; j < 4; ++j) b[j] = *(const float4*)&sB[tc + j][k];
            for (int i = 0; i < 4; ++i)
                for (int j = 0; j < 4; ++j)
                    acc[i][j] = fmaf(a[i].x, b[j].x,
                                fmaf(a[i].y, b[j].y,
                                fmaf(a[i].z, b[j].z,
                                fmaf(a[i].w, b[j].w, acc[i][j]))));
        }
        for (int i = 0; i < 4; ++i) {
            int gn = node0 + tr + i;
            if (gn >= N_NODES) continue;
            int gc = col0 + tc;
            if (gc < DIM) {
                *(float4*)&y[gn * DIM + gc] =
                    make_float4(acc[i][0], acc[i][1], acc[i][2], acc[i][3]);
            } else {
                int c = gc - DIM;
                *(float4*)&r[gn * DIM + c] =
                    make_float4(acc[i][0] + b1[c], acc[i][1] + b1[c + 1],
                                acc[i][2] + b1[c + 2], acc[i][3] + b1[c + 3]);
            }
        }
    } else if (blk < NB_GEMM + NB_HIST) {
        // ------------------- dst-bucket histogram ---------------------------
        const int hb = blk - NB_GEMM;
        for (int i = t; i < NBUCK; i += 256) lhist[i] = 0;
        __syncthreads();
        const int e0 = hb * EPB;
        for (int i = 0; i < 8; ++i) {
            int e = e0 + i * 256 + t;
            if (e < N_EDGES) atomicAdd(&lhist[dst[e] >> 6], 1);
        }
        __syncthreads();
        for (int i = t; i < NBUCK; i += 256)
            if (lhist[i]) atomicAdd(&ghist[i], lhist[i]);
        __syncthreads();
        if (t == 0) {
            __threadfence();
            int old = atomicAdd(ticket_hist, 1);
            islast = (old == NB_HIST - 1);
        }
        __syncthreads();
        if (islast) {
            __threadfence();
            if (t < 64) {
                int carry = 0;
                for (int c = 0; c < 5; ++c) {  // 5*64 = 320 >= 313
                    int idx = c * 64 + t;
                    int v = (idx < NBUCK)
                        ? __hip_atomic_load(&ghist[idx], __ATOMIC_RELAXED,
                                            __HIP_MEMORY_SCOPE_AGENT)
                        : 0;
                    int xv = v;
                    for (int s = 1; s < 64; s <<= 1) {
                        int u = __shfl_up(xv, s);
                        if (t >= s) xv += u;
                    }
                    int excl = carry + xv - v;
                    if (idx < NBUCK) { boff[idx] = excl; gcursor[idx] = excl; }
                    carry += __shfl(xv, 63);
                }
                if (t == 0) boff[NBUCK] = carry;  // == N_EDGES
            }
        }
    } else {
        // ------------------- params: vrel, vroot, cb3 (one wave) ------------
        if (t < 64) {
            for (int kk = 0; kk < 2; ++kk) {
                int k = t + kk * 64;
                float sr = 0.f, so = 0.f;
                for (int h = 0; h < DIM; ++h) {
                    float wl = Wlin[h];
                    sr = fmaf(wl, W3rel[h * DIM + k], sr);
                    so = fmaf(wl, W3root[h * DIM + k], so);
                }
                vrel[k] = sr;
                vroot[k] = so;
            }
            float c = b3[t] * Wlin[t] + b3[t + 64] * Wlin[t + 64];
            for (int m = 32; m > 0; m >>= 1) c += __shfl_xor(c, m);
            if (t == 0) cb3[0] = c;
        }
    }
}

// ---------------------------------------------------------------------------
// K_partition: scatter edges into dst-buckets (runs of ~6.5 recs per block)
// record = ((dst&63)<<16 | src, bits(w))
// ---------------------------------------------------------------------------
__global__ __launch_bounds__(256) void k_partition(const int* __restrict__ src,
                                                   const int* __restrict__ dst,
                                                   const float* __restrict__ ew,
                                                   int* __restrict__ gcursor,
                                                   int2* __restrict__ part) {
    __shared__ int lhist[NBUCK], gbase[NBUCK], lcur[NBUCK];
    const int t = threadIdx.x;
    for (int i = t; i < NBUCK; i += 256) lhist[i] = 0;
    __syncthreads();
    const int e0 = blockIdx.x * EPB;
    int mys[8], myd[8];
    float myw[8];
    for (int i = 0; i < 8; ++i) {
        int e = e0 + i * 256 + t;
        if (e < N_EDGES) {
            mys[i] = src[e];
            myd[i] = dst[e];
            myw[i] = ew[e];
            atomicAdd(&lhist[myd[i] >> 6], 1);
        } else {
            myd[i] = -1;
        }
    }
    __syncthreads();
    for (int i = t; i < NBUCK; i += 256) {
        gbase[i] = lhist[i] ? atomicAdd(&gcursor[i], lhist[i]) : 0;
        lcur[i] = 0;
    }
    __syncthreads();
    for (int i = 0; i < 8; ++i) {
        if (myd[i] >= 0) {
            int b = myd[i] >> 6;
            int rk = atomicAdd(&lcur[b], 1);
            part[gbase[b] + rk] =
                make_int2(((myd[i] & 63) << 16) | mys[i], __float_as_int(myw[i]));
        }
    }
}

// ---------------------------------------------------------------------------
// K_bucketsort: within each bucket, counting-sort records by node; emit CSR off
// ---------------------------------------------------------------------------
__global__ __launch_bounds__(256) void k_bucketsort(const int* __restrict__ boff,
                                                    const int2* __restrict__ part,
                                                    int2* __restrict__ sorted,
                                                    int* __restrict__ off) {
    __shared__ int nh[64], ncur[64];
    const int b = blockIdx.x;
    const int t = threadIdx.x;
    const int s0 = boff[b], s1 = boff[b + 1];
    if (t < 64) nh[t] = 0;
    __syncthreads();
    for (int i = s0 + t; i < s1; i += 256) atomicAdd(&nh[part[i].x >> 16], 1);
    __syncthreads();
    if (t < 64) {
        int v = nh[t];
        int xv = v;
        for (int s = 1; s < 64; s <<= 1) {
            int u = __shfl_up(xv, s);
            if (t >= s) xv += u;
        }
        int excl = xv - v;
        ncur[t] = excl;
        int node = b * 64 + t;
        if (node < N_NODES) off[node] = s0 + excl;
    }
    __syncthreads();
    for (int i = s0 + t; i < s1; i += 256) {
        int2 rc = part[i];
        int dl = rc.x >> 16;
        int p = atomicAdd(&ncur[dl], 1);
        sorted[s0 + p] = make_int2(rc.x & 0xFFFF, rc.y);
    }
    if (b == 0 && t == 0) off[N_NODES] = N_EDGES;
}

// ---------------------------------------------------------------------------
// K_agg: wave per node; agg y rows; h1=relu(agg+r); a=h.vrel, b=h.vroot
// ---------------------------------------------------------------------------
__global__ __launch_bounds__(256) void k_agg(const float2* __restrict__ y2,
                                             const float2* __restrict__ r2,
                                             const int* __restrict__ off,
                                             const int2* __restrict__ grec,
                                             const float2* __restrict__ vrel2,
                                             const float2* __restrict__ vroot2,
                                             float* __restrict__ aout,
                                             float* __restrict__ bout) {
    const int lane = threadIdx.x & 63;
    const int node = blockIdx.x * 4 + (threadIdx.x >> 6);
    if (node >= N_NODES) return;

    int j = off[node];
    const int e1 = off[node + 1];
    float sx = 0.f, sy = 0.f;
    for (; j + 4 <= e1; j += 4) {
        int2 r0 = grec[j], r1 = grec[j + 1], rr2 = grec[j + 2], r3 = grec[j + 3];
        float w0 = __int_as_float(r0.y), w1 = __int_as_float(r1.y);
        float w2 = __int_as_float(rr2.y), w3 = __int_as_float(r3.y);
        float2 v0 = y2[r0.x * 64 + lane];
        float2 v1 = y2[r1.x * 64 + lane];
        float2 v2 = y2[rr2.x * 64 + lane];
        float2 v3 = y2[r3.x * 64 + lane];
        sx = fmaf(w0, v0.x, fmaf(w1, v1.x, fmaf(w2, v2.x, fmaf(w3, v3.x, sx))));
        sy = fmaf(w0, v0.y, fmaf(w1, v1.y, fmaf(w2, v2.y, fmaf(w3, v3.y, sy))));
    }
    for (; j < e1; ++j) {
        int2 rc = grec[j];
        float w = __int_as_float(rc.y);
        float2 v = y2[rc.x * 64 + lane];
        sx = fmaf(w, v.x, sx);
        sy = fmaf(w, v.y, sy);
    }
    float2 rr = r2[node * 64 + lane];
    float hx = fmaxf(sx + rr.x, 0.f);
    float hy = fmaxf(sy + rr.y, 0.f);
    float2 vr = vrel2[lane];
    float2 vo = vroot2[lane];
    float pa = hx * vr.x + hy * vr.y;
    float pb = hx * vo.x + hy * vo.y;
    for (int m = 32; m > 0; m >>= 1) {
        pa += __shfl_xor(pa, m);
        pb += __shfl_xor(pb, m);
    }
    if (lane == 0) {
        aout[node] = pa;
        bout[node] = pb;
    }
}

// ---------------------------------------------------------------------------
// K_reduce_final: wave per node: s=sum w*a[src] over node's run; bin by graph;
// spread-partial global flush; last block computes out[]
// ---------------------------------------------------------------------------
__global__ __launch_bounds__(256) void k_reduce_final(
    const int2* __restrict__ sorted, const int* __restrict__ off,
    const float* __restrict__ a, const float* __restrict__ bvec,
    const int* __restrict__ batch,
    float* __restrict__ gpart, int* __restrict__ gpartc,
    int* __restrict__ ticket_red,
    const float* __restrict__ cb3, const float* __restrict__ blin,
    float* __restrict__ out) {
    __shared__ float sbin[NGRAPH];
    __shared__ int cbin[NGRAPH];
    __shared__ int islast;
    const int t = threadIdx.x;
    for (int i = t; i < NGRAPH; i += 256) { sbin[i] = 0.f; cbin[i] = 0; }
    __syncthreads();
    const int lane = t & 63;
    const int gw = blockIdx.x * 4 + (t >> 6);
    const int nw = gridDim.x * 4;
    for (int node = gw; node < N_NODES; node += nw) {
        const int e0 = off[node], e1 = off[node + 1];
        float s = 0.f;
        for (int j = e0 + lane; j < e1; j += 64) {
            int2 rc = sorted[j];
            s = fmaf(__int_as_float(rc.y), a[rc.x], s);
        }
        for (int m = 32; m > 0; m >>= 1) s += __shfl_xor(s, m);
        if (lane == 0) {
            int g = batch[node];
            atomicAdd(&sbin[g], s + bvec[node]);
            atomicAdd(&cbin[g], 1);
        }
    }
    __syncthreads();
    const int slot = blockIdx.x & 63;
    for (int i = t; i < NGRAPH; i += 256) {
        atomicAdd(&gpart[slot * NGRAPH + i], sbin[i]);
        if (cbin[i]) atomicAdd(&gpartc[slot * NGRAPH + i], cbin[i]);
    }
    __syncthreads();
    if (t == 0) {
        __threadfence();
        islast = (atomicAdd(ticket_red, 1) == (int)gridDim.x - 1);
    }
    __syncthreads();
    if (islast) {
        __threadfence();
        if (t < NGRAPH) {
            float S = 0.f;
            int C = 0;
            for (int s2 = 0; s2 < 64; ++s2) {
                S += __hip_atomic_load(&gpart[s2 * NGRAPH + t], __ATOMIC_RELAXED,
                                       __HIP_MEMORY_SCOPE_AGENT);
                C += __hip_atomic_load(&gpartc[s2 * NGRAPH + t], __ATOMIC_RELAXED,
                                       __HIP_MEMORY_SCOPE_AGENT);
            }
            float denom = (C > 0) ? (float)C : 1.f;
            float v = (S + (float)C * cb3[0]) / denom + blin[0];
            out[t] = (v > 0.f) ? v : 0.f;
        }
    }
}

// ---------------------------------------------------------------------------
extern "C" void kernel_launch(void* const* d_in, const int* in_sizes, int n_in,
                              void* d_out, int out_size, void* d_ws, size_t ws_size,
                              hipStream_t stream) {
    const float* x = (const float*)d_in[0];
    const int* edge_index = (const int*)d_in[1];
    const int* src = edge_index;
    const int* dst = edge_index + N_EDGES;
    const int* batch = (const int*)d_in[2];
    const float* ew = (const float*)d_in[3];
    const float* W1rel = (const float*)d_in[4];
    const float* b1 = (const float*)d_in[5];
    const float* W1root = (const float*)d_in[6];
    const float* W3rel = (const float*)d_in[7];
    const float* b3 = (const float*)d_in[8];
    const float* W3root = (const float*)d_in[9];
    const float* Wlin = (const float*)d_in[10];
    const float* blin = (const float*)d_in[11];
    float* out = (float*)d_out;

    char* w = (char*)d_ws;
    size_t o = 0;
    auto alloc = [&](size_t bytes) -> void* {
        void* p = w + o;
        o += bytes;
        o = (o + 255) & ~(size_t)255;
        return p;
    };
    // zero-init region (single memset): ghist | tickets | gpart | gpartc
    char* zbase = (char*)alloc(1280 + 64 * NGRAPH * 4 * 2);
    int* ghist = (int*)zbase;                       // 313 ints
    int* ticket_hist = ghist + NBUCK;               // 1
    int* ticket_red = ghist + NBUCK + 1;            // 1
    float* gpart = (float*)(zbase + 1280);          // 64*64 floats
    int* gpartc = (int*)(zbase + 1280 + 64 * NGRAPH * 4);
    const size_t zbytes = 1280 + 64 * NGRAPH * 4 * 2;

    float* y = (float*)alloc((size_t)N_NODES * DIM * 4);
    float* r = (float*)alloc((size_t)N_NODES * DIM * 4);
    int* boff = (int*)alloc((size_t)(NBUCK + 1) * 4);
    int* gcursor = (int*)alloc((size_t)NBUCK * 4);
    int2* part = (int2*)alloc((size_t)N_EDGES * 8);
    int2* sorted = (int2*)alloc((size_t)N_EDGES * 8);
    int* off = (int*)alloc((size_t)(N_NODES + 1) * 4);
    float* a = (float*)alloc((size_t)N_NODES * 4);
    float* b = (float*)alloc((size_t)N_NODES * 4);
    float* vrel = (float*)alloc(DIM * 4);
    float* vroot = (float*)alloc(DIM * 4);
    float* cb3 = (float*)alloc(4);

    hipMemsetAsync(zbase, 0, zbytes, stream);

    k_front<<<NB_GEMM + NB_HIST + 1, 256, 0, stream>>>(
        x, W1rel, W1root, b1, y, r, dst, ghist, ticket_hist, boff, gcursor,
        W3rel, W3root, b3, Wlin, vrel, vroot, cb3);

    k_partition<<<NB_HIST, 256, 0, stream>>>(src, dst, ew, gcursor, part);

    k_bucketsort<<<NBUCK, 256, 0, stream>>>(boff, part, sorted, off);

    k_agg<<<(N_NODES + 3) / 4, 256, 0, stream>>>(
        (const float2*)y, (const float2*)r, off, sorted,
        (const float2*)vrel, (const float2*)vroot, a, b);

    k_reduce_final<<<RED_BLOCKS, 256, 0, stream>>>(
        sorted, off, a, b, batch, gpart, gpartc, ticket_red, cb3, blin, out);
}

// Round 5
// 197.469 us; speedup vs baseline: 2.3577x; 1.0873x over previous
//
#include <hip/hip_runtime.h>

#define N_NODES 20000
#define N_EDGES 640000
#define DIM 128
#define NGRAPH 64
#define NBUCK 313          // ceil(20000/64) dst buckets of 64 nodes
#define EPB 2048           // edges per histogram/partition block
#define NB_GEMM 1252       // 313 node-tiles x 4 col-tiles
#define NB_HIST 313        // ceil(640000/2048)
#define RED_BLOCKS 512

// round-to-nearest-even fp32 -> bf16 (as ushort)
__device__ __forceinline__ unsigned int bf16rne(float f) {
    unsigned int u = __float_as_uint(f);
    return (u + 0x7FFFu + ((u >> 16) & 1u)) >> 16;
}

// ---------------------------------------------------------------------------
// K_front: fused [GEMM | dst-bucket histogram (+scan via last-block ticket) | params]
// y output is bf16; sB uses XOR swizzle (k4 ^ ((c>>2)&7)) to kill 8-way LDS
// bank conflicts (stride 132 ≡ 4 mod 32 put all B-reads in banks {0,16}).
// ---------------------------------------------------------------------------
__global__ __launch_bounds__(256, 2) void k_front(
    const float* __restrict__ x, const float* __restrict__ Wrel,
    const float* __restrict__ Wroot, const float* __restrict__ b1,
    unsigned int* __restrict__ yb, float* __restrict__ r,
    const int* __restrict__ dst,
    int* __restrict__ ghist, int* __restrict__ ticket_hist,
    int* __restrict__ boff, int* __restrict__ gcursor,
    const float* __restrict__ W3rel, const float* __restrict__ W3root,
    const float* __restrict__ b3, const float* __restrict__ Wlin,
    float* __restrict__ vrel, float* __restrict__ vroot, float* __restrict__ cb3) {

    __shared__ float sA[64][132];
    __shared__ float sB[64][132];
    __shared__ int lhist[NBUCK];
    __shared__ int islast;

    const int t = threadIdx.x;
    const int blk = blockIdx.x;

    if (blk < NB_GEMM) {
        const int node0 = (blk % 313) * 64;
        const int col0 = (blk / 313) * 64;

        for (int ch = 0; ch < 8; ++ch) {
            int idx = ch * 256 + t;
            int row = idx >> 5;
            int k4 = idx & 31;
            int gn = node0 + row;
            float4 v = make_float4(0.f, 0.f, 0.f, 0.f);
            if (gn < N_NODES) v = ((const float4*)x)[gn * 32 + k4];
            *(float4*)&sA[row][k4 * 4] = v;
        }
        for (int ch = 0; ch < 8; ++ch) {
            int idx = ch * 256 + t;
            int c = idx >> 5;
            int k4 = idx & 31;
            int gc = col0 + c;
            const float* srcw = (gc < DIM) ? (Wrel + gc * DIM) : (Wroot + (gc - DIM) * DIM);
            float4 v = ((const float4*)srcw)[k4];
            int swk = k4 ^ ((c >> 2) & 7);   // XOR swizzle
            *(float4*)&sB[c][swk * 4] = v;
        }
        __syncthreads();

        const int tr = (t >> 4) * 4;
        const int tc = (t & 15) * 4;
        const int u7 = t & 7;                // read-side swizzle key: (tc+j)>>2 & 7
        float acc[4][4] = {};
        for (int k4 = 0; k4 < 32; ++k4) {
            const int k = k4 * 4;
            const int swk = (k4 ^ u7) * 4;
            float4 a[4], b[4];
            for (int i = 0; i < 4; ++i) a[i] = *(const float4*)&sA[tr + i][k];
            for (int j = 0; j < 4; ++j) b[j] = *(const float4*)&sB[tc + j][swk];
            for (int i = 0; i < 4; ++i)
                for (int j = 0; j < 4; ++j)
                    acc[i][j] = fmaf(a[i].x, b[j].x,
                                fmaf(a[i].y, b[j].y,
                                fmaf(a[i].z, b[j].z,
                                fmaf(a[i].w, b[j].w, acc[i][j]))));
        }
        for (int i = 0; i < 4; ++i) {
            int gn = node0 + tr + i;
            if (gn >= N_NODES) continue;
            int gc = col0 + tc;
            if (gc < DIM) {
                // bf16 pack: 4 cols -> uint2
                uint2 p;
                p.x = bf16rne(acc[i][0]) | (bf16rne(acc[i][1]) << 16);
                p.y = bf16rne(acc[i][2]) | (bf16rne(acc[i][3]) << 16);
                *(uint2*)&yb[gn * 64 + (gc >> 1)] = p;
            } else {
                int c = gc - DIM;
                *(float4*)&r[gn * DIM + c] =
                    make_float4(acc[i][0] + b1[c], acc[i][1] + b1[c + 1],
                                acc[i][2] + b1[c + 2], acc[i][3] + b1[c + 3]);
            }
        }
    } else if (blk < NB_GEMM + NB_HIST) {
        const int hb = blk - NB_GEMM;
        for (int i = t; i < NBUCK; i += 256) lhist[i] = 0;
        __syncthreads();
        const int e0 = hb * EPB;
        for (int i = 0; i < 8; ++i) {
            int e = e0 + i * 256 + t;
            if (e < N_EDGES) atomicAdd(&lhist[dst[e] >> 6], 1);
        }
        __syncthreads();
        for (int i = t; i < NBUCK; i += 256)
            if (lhist[i]) atomicAdd(&ghist[i], lhist[i]);
        __syncthreads();
        if (t == 0) {
            __threadfence();
            int old = atomicAdd(ticket_hist, 1);
            islast = (old == NB_HIST - 1);
        }
        __syncthreads();
        if (islast) {
            __threadfence();
            if (t < 64) {
                int carry = 0;
                for (int c = 0; c < 5; ++c) {
                    int idx = c * 64 + t;
                    int v = (idx < NBUCK)
                        ? __hip_atomic_load(&ghist[idx], __ATOMIC_RELAXED,
                                            __HIP_MEMORY_SCOPE_AGENT)
                        : 0;
                    int xv = v;
                    for (int s = 1; s < 64; s <<= 1) {
                        int u = __shfl_up(xv, s);
                        if (t >= s) xv += u;
                    }
                    int excl = carry + xv - v;
                    if (idx < NBUCK) { boff[idx] = excl; gcursor[idx] = excl; }
                    carry += __shfl(xv, 63);
                }
                if (t == 0) boff[NBUCK] = carry;
            }
        }
    } else {
        if (t < 64) {
            for (int kk = 0; kk < 2; ++kk) {
                int k = t + kk * 64;
                float sr = 0.f, so = 0.f;
                for (int h = 0; h < DIM; ++h) {
                    float wl = Wlin[h];
                    sr = fmaf(wl, W3rel[h * DIM + k], sr);
                    so = fmaf(wl, W3root[h * DIM + k], so);
                }
                vrel[k] = sr;
                vroot[k] = so;
            }
            float c = b3[t] * Wlin[t] + b3[t + 64] * Wlin[t + 64];
            for (int m = 32; m > 0; m >>= 1) c += __shfl_xor(c, m);
            if (t == 0) cb3[0] = c;
        }
    }
}

// ---------------------------------------------------------------------------
// K_partition: scatter edges into dst-buckets
// ---------------------------------------------------------------------------
__global__ __launch_bounds__(256) void k_partition(const int* __restrict__ src,
                                                   const int* __restrict__ dst,
                                                   const float* __restrict__ ew,
                                                   int* __restrict__ gcursor,
                                                   int2* __restrict__ part) {
    __shared__ int lhist[NBUCK], gbase[NBUCK], lcur[NBUCK];
    const int t = threadIdx.x;
    for (int i = t; i < NBUCK; i += 256) lhist[i] = 0;
    __syncthreads();
    const int e0 = blockIdx.x * EPB;
    int mys[8], myd[8];
    float myw[8];
    for (int i = 0; i < 8; ++i) {
        int e = e0 + i * 256 + t;
        if (e < N_EDGES) {
            mys[i] = src[e];
            myd[i] = dst[e];
            myw[i] = ew[e];
            atomicAdd(&lhist[myd[i] >> 6], 1);
        } else {
            myd[i] = -1;
        }
    }
    __syncthreads();
    for (int i = t; i < NBUCK; i += 256) {
        gbase[i] = lhist[i] ? atomicAdd(&gcursor[i], lhist[i]) : 0;
        lcur[i] = 0;
    }
    __syncthreads();
    for (int i = 0; i < 8; ++i) {
        if (myd[i] >= 0) {
            int b = myd[i] >> 6;
            int rk = atomicAdd(&lcur[b], 1);
            part[gbase[b] + rk] =
                make_int2(((myd[i] & 63) << 16) | mys[i], __float_as_int(myw[i]));
        }
    }
}

// ---------------------------------------------------------------------------
// K_bucketsort: within each bucket, counting-sort records by node; emit CSR off
// ---------------------------------------------------------------------------
__global__ __launch_bounds__(256) void k_bucketsort(const int* __restrict__ boff,
                                                    const int2* __restrict__ part,
                                                    int2* __restrict__ sorted,
                                                    int* __restrict__ off) {
    __shared__ int nh[64], ncur[64];
    const int b = blockIdx.x;
    const int t = threadIdx.x;
    const int s0 = boff[b], s1 = boff[b + 1];
    if (t < 64) nh[t] = 0;
    __syncthreads();
    for (int i = s0 + t; i < s1; i += 256) atomicAdd(&nh[part[i].x >> 16], 1);
    __syncthreads();
    if (t < 64) {
        int v = nh[t];
        int xv = v;
        for (int s = 1; s < 64; s <<= 1) {
            int u = __shfl_up(xv, s);
            if (t >= s) xv += u;
        }
        int excl = xv - v;
        ncur[t] = excl;
        int node = b * 64 + t;
        if (node < N_NODES) off[node] = s0 + excl;
    }
    __syncthreads();
    for (int i = s0 + t; i < s1; i += 256) {
        int2 rc = part[i];
        int dl = rc.x >> 16;
        int p = atomicAdd(&ncur[dl], 1);
        sorted[s0 + p] = make_int2(rc.x & 0xFFFF, rc.y);
    }
    if (b == 0 && t == 0) off[N_NODES] = N_EDGES;
}

// ---------------------------------------------------------------------------
// K_agg: wave per node; gather bf16 y rows; h1=relu(agg+r); a=h.vrel, b=h.vroot
// ---------------------------------------------------------------------------
__global__ __launch_bounds__(256) void k_agg(const unsigned int* __restrict__ yb,
                                             const float2* __restrict__ r2,
                                             const int* __restrict__ off,
                                             const int2* __restrict__ grec,
                                             const float2* __restrict__ vrel2,
                                             const float2* __restrict__ vroot2,
                                             float* __restrict__ aout,
                                             float* __restrict__ bout) {
    const int lane = threadIdx.x & 63;
    const int node = blockIdx.x * 4 + (threadIdx.x >> 6);
    if (node >= N_NODES) return;

    int j = off[node];
    const int e1 = off[node + 1];
    float sx = 0.f, sy = 0.f;
    for (; j + 4 <= e1; j += 4) {
        int2 r0 = grec[j], r1 = grec[j + 1], rr2 = grec[j + 2], r3 = grec[j + 3];
        float w0 = __int_as_float(r0.y), w1 = __int_as_float(r1.y);
        float w2 = __int_as_float(rr2.y), w3 = __int_as_float(r3.y);
        unsigned int v0 = yb[r0.x * 64 + lane];
        unsigned int v1 = yb[r1.x * 64 + lane];
        unsigned int v2 = yb[rr2.x * 64 + lane];
        unsigned int v3 = yb[r3.x * 64 + lane];
        sx = fmaf(w0, __uint_as_float(v0 << 16),
             fmaf(w1, __uint_as_float(v1 << 16),
             fmaf(w2, __uint_as_float(v2 << 16),
             fmaf(w3, __uint_as_float(v3 << 16), sx))));
        sy = fmaf(w0, __uint_as_float(v0 & 0xFFFF0000u),
             fmaf(w1, __uint_as_float(v1 & 0xFFFF0000u),
             fmaf(w2, __uint_as_float(v2 & 0xFFFF0000u),
             fmaf(w3, __uint_as_float(v3 & 0xFFFF0000u), sy))));
    }
    for (; j < e1; ++j) {
        int2 rc = grec[j];
        float w = __int_as_float(rc.y);
        unsigned int v = yb[rc.x * 64 + lane];
        sx = fmaf(w, __uint_as_float(v << 16), sx);
        sy = fmaf(w, __uint_as_float(v & 0xFFFF0000u), sy);
    }
    float2 rr = r2[node * 64 + lane];
    float hx = fmaxf(sx + rr.x, 0.f);
    float hy = fmaxf(sy + rr.y, 0.f);
    float2 vr = vrel2[lane];
    float2 vo = vroot2[lane];
    float pa = hx * vr.x + hy * vr.y;
    float pb = hx * vo.x + hy * vo.y;
    for (int m = 32; m > 0; m >>= 1) {
        pa += __shfl_xor(pa, m);
        pb += __shfl_xor(pb, m);
    }
    if (lane == 0) {
        aout[node] = pa;
        bout[node] = pb;
    }
}

// ---------------------------------------------------------------------------
// K_reduce_final: wave per node; bin by graph; spread partials; last block -> out
// ---------------------------------------------------------------------------
__global__ __launch_bounds__(256) void k_reduce_final(
    const int2* __restrict__ sorted, const int* __restrict__ off,
    const float* __restrict__ a, const float* __restrict__ bvec,
    const int* __restrict__ batch,
    float* __restrict__ gpart, int* __restrict__ gpartc,
    int* __restrict__ ticket_red,
    const float* __restrict__ cb3, const float* __restrict__ blin,
    float* __restrict__ out) {
    __shared__ float sbin[NGRAPH];
    __shared__ int cbin[NGRAPH];
    __shared__ int islast;
    const int t = threadIdx.x;
    for (int i = t; i < NGRAPH; i += 256) { sbin[i] = 0.f; cbin[i] = 0; }
    __syncthreads();
    const int lane = t & 63;
    const int gw = blockIdx.x * 4 + (t >> 6);
    const int nw = gridDim.x * 4;
    for (int node = gw; node < N_NODES; node += nw) {
        const int e0 = off[node], e1 = off[node + 1];
        float s = 0.f;
        for (int j = e0 + lane; j < e1; j += 64) {
            int2 rc = sorted[j];
            s = fmaf(__int_as_float(rc.y), a[rc.x], s);
        }
        for (int m = 32; m > 0; m >>= 1) s += __shfl_xor(s, m);
        if (lane == 0) {
            int g = batch[node];
            atomicAdd(&sbin[g], s + bvec[node]);
            atomicAdd(&cbin[g], 1);
        }
    }
    __syncthreads();
    const int slot = blockIdx.x & 63;
    for (int i = t; i < NGRAPH; i += 256) {
        atomicAdd(&gpart[slot * NGRAPH + i], sbin[i]);
        if (cbin[i]) atomicAdd(&gpartc[slot * NGRAPH + i], cbin[i]);
    }
    __syncthreads();
    if (t == 0) {
        __threadfence();
        islast = (atomicAdd(ticket_red, 1) == (int)gridDim.x - 1);
    }
    __syncthreads();
    if (islast) {
        __threadfence();
        if (t < NGRAPH) {
            float S = 0.f;
            int C = 0;
            for (int s2 = 0; s2 < 64; ++s2) {
                S += __hip_atomic_load(&gpart[s2 * NGRAPH + t], __ATOMIC_RELAXED,
                                       __HIP_MEMORY_SCOPE_AGENT);
                C += __hip_atomic_load(&gpartc[s2 * NGRAPH + t], __ATOMIC_RELAXED,
                                       __HIP_MEMORY_SCOPE_AGENT);
            }
            float denom = (C > 0) ? (float)C : 1.f;
            float v = (S + (float)C * cb3[0]) / denom + blin[0];
            out[t] = (v > 0.f) ? v : 0.f;
        }
    }
}

// ---------------------------------------------------------------------------
extern "C" void kernel_launch(void* const* d_in, const int* in_sizes, int n_in,
                              void* d_out, int out_size, void* d_ws, size_t ws_size,
                              hipStream_t stream) {
    const float* x = (const float*)d_in[0];
    const int* edge_index = (const int*)d_in[1];
    const int* src = edge_index;
    const int* dst = edge_index + N_EDGES;
    const int* batch = (const int*)d_in[2];
    const float* ew = (const float*)d_in[3];
    const float* W1rel = (const float*)d_in[4];
    const float* b1 = (const float*)d_in[5];
    const float* W1root = (const float*)d_in[6];
    const float* W3rel = (const float*)d_in[7];
    const float* b3 = (const float*)d_in[8];
    const float* W3root = (const float*)d_in[9];
    const float* Wlin = (const float*)d_in[10];
    const float* blin = (const float*)d_in[11];
    float* out = (float*)d_out;

    char* w = (char*)d_ws;
    size_t o = 0;
    auto alloc = [&](size_t bytes) -> void* {
        void* p = w + o;
        o += bytes;
        o = (o + 255) & ~(size_t)255;
        return p;
    };
    char* zbase = (char*)alloc(1280 + 64 * NGRAPH * 4 * 2);
    int* ghist = (int*)zbase;
    int* ticket_hist = ghist + NBUCK;
    int* ticket_red = ghist + NBUCK + 1;
    float* gpart = (float*)(zbase + 1280);
    int* gpartc = (int*)(zbase + 1280 + 64 * NGRAPH * 4);
    const size_t zbytes = 1280 + 64 * NGRAPH * 4 * 2;

    unsigned int* yb = (unsigned int*)alloc((size_t)N_NODES * DIM * 2);  // bf16
    float* r = (float*)alloc((size_t)N_NODES * DIM * 4);
    int* boff = (int*)alloc((size_t)(NBUCK + 1) * 4);
    int* gcursor = (int*)alloc((size_t)NBUCK * 4);
    int2* part = (int2*)alloc((size_t)N_EDGES * 8);
    int2* sorted = (int2*)alloc((size_t)N_EDGES * 8);
    int* off = (int*)alloc((size_t)(N_NODES + 1) * 4);
    float* a = (float*)alloc((size_t)N_NODES * 4);
    float* b = (float*)alloc((size_t)N_NODES * 4);
    float* vrel = (float*)alloc(DIM * 4);
    float* vroot = (float*)alloc(DIM * 4);
    float* cb3 = (float*)alloc(4);

    hipMemsetAsync(zbase, 0, zbytes, stream);

    k_front<<<NB_GEMM + NB_HIST + 1, 256, 0, stream>>>(
        x, W1rel, W1root, b1, yb, r, dst, ghist, ticket_hist, boff, gcursor,
        W3rel, W3root, b3, Wlin, vrel, vroot, cb3);

    k_partition<<<NB_HIST, 256, 0, stream>>>(src, dst, ew, gcursor, part);

    k_bucketsort<<<NBUCK, 256, 0, stream>>>(boff, part, sorted, off);

    k_agg<<<(N_NODES + 3) / 4, 256, 0, stream>>>(
        yb, (const float2*)r, off, sorted,
        (const float2*)vrel, (const float2*)vroot, a, b);

    k_reduce_final<<<RED_BLOCKS, 256, 0, stream>>>(
        sorted, off, a, b, batch, gpart, gpartc, ticket_red, cb3, blin, out);
}